// Round 4
// baseline (4828.582 us; speedup 1.0000x reference)
//
#include <hip/hip_runtime.h>
#include <stdint.h>

// ContTimeLSTM: B=128, L=512, I=256, D=512.
// Inputs f32 (x, dt, bos, W, bias) + int32 seq_lens. Output f32.
// bf16 used internally for the MFMA projection (tolerance floor 8*eps_bf16).
constexpr int B_   = 128;
constexpr int L_   = 512;
constexpr int I_   = 256;
constexpr int D_   = 512;
constexpr int KTOT = I_ + D_;     // 768
constexpr int ND7  = 7 * D_;      // 3584
constexpr int RW   = 16;          // rows per workgroup
constexpr int MW   = 16;          // m (state dim) per workgroup
constexpr int RG   = B_ / RW;     // 8 row groups (one per XCD: rg = bid & 7)
constexpr int MG   = D_ / MW;     // 32 m groups = blocks per row-group barrier
constexpr int NWG  = RG * MG;     // 256 workgroups (1 per CU)
constexpr int NTHR = 256;         // 4 waves
constexpr int PS   = 122;         // padded LDS row stride (floats)

typedef short  bfrag8 __attribute__((ext_vector_type(8)));  // 8 bf16 (4 VGPRs)
typedef float  f32x4  __attribute__((ext_vector_type(4)));

__device__ __forceinline__ unsigned short f2bf(float f) {
    union { float f; uint32_t i; } v; v.f = f;
    uint32_t x = v.i;
    return (unsigned short)((x + 0x7fffu + ((x >> 16) & 1u)) >> 16);  // RNE
}
__device__ __forceinline__ bfrag8 pack8(float4 a, float4 b) {
    bfrag8 r;
    r[0] = (short)f2bf(a.x); r[1] = (short)f2bf(a.y);
    r[2] = (short)f2bf(a.z); r[3] = (short)f2bf(a.w);
    r[4] = (short)f2bf(b.x); r[5] = (short)f2bf(b.y);
    r[6] = (short)f2bf(b.z); r[7] = (short)f2bf(b.w);
    return r;
}
__device__ __forceinline__ float sigm(float x) { return 1.0f / (1.0f + __expf(-x)); }
__device__ __forceinline__ float tanh_f(float x) {
    float xc = fminf(fmaxf(x, -15.f), 15.f);
    float e  = __expf(2.f * xc);
    return (e - 1.f) / (e + 1.f);
}
__device__ __forceinline__ float softplus_f(float x) {
    return (x > 15.f) ? x : log1pf(__expf(x));
}

// Per-row-group barrier (32 blocks, same XCD under round-robin dispatch).
// Arrival: ACQ_REL fetch_add (release publishes HBUF stores).
// Wait: relaxed spin (no per-poll cache invalidate), one acquire fence on exit.
__device__ __forceinline__ void gbar(int* cnt, int* gen, int gexp) {
    __syncthreads();
    if (threadIdx.x == 0) {
        int v = __hip_atomic_fetch_add(cnt, 1, __ATOMIC_ACQ_REL,
                                       __HIP_MEMORY_SCOPE_AGENT);
        if (v == MG - 1) {
            __hip_atomic_store(cnt, 0, __ATOMIC_RELAXED, __HIP_MEMORY_SCOPE_AGENT);
            __hip_atomic_store(gen, gexp, __ATOMIC_RELEASE, __HIP_MEMORY_SCOPE_AGENT);
        } else {
            while (__hip_atomic_load(gen, __ATOMIC_RELAXED,
                                     __HIP_MEMORY_SCOPE_AGENT) < gexp) {
                __builtin_amdgcn_s_sleep(1);
            }
            __builtin_amdgcn_fence(__ATOMIC_ACQUIRE, "agent");  // L1+L2 inv once
        }
    }
    __syncthreads();
}

// Prologue: proj0[j] = dot(W[j, 0:I], bos) + bias[j]  (BOS step, zero state)
__global__ void bos_proj_kernel(const float* __restrict__ W,
                                const float* __restrict__ bos,
                                const float* __restrict__ bias,
                                float* __restrict__ proj0) {
    int j = blockIdx.x * blockDim.x + threadIdx.x;
    if (j >= ND7) return;
    const float* wr = W + (size_t)j * KTOT;
    float s = 0.f;
#pragma unroll 8
    for (int k = 0; k < I_; ++k) s += wr[k] * bos[k];
    proj0[j] = s + bias[j];
}

// Persistent recurrence kernel.
// WG (rg,mg): rows b0..b0+15, state dims m0..m0+15, proj cols {g*512+m0+0..15}.
// Weights pinned in VGPRs (bf16): wave w holds K-steps s = w+4i (i=0..5), 7 N-tiles.
__global__ void __launch_bounds__(NTHR, 1)
ctlstm_kernel(const float* __restrict__ X,     // (B,L,I) f32
              const float* __restrict__ DT,    // (B,L)   f32
              const int*   __restrict__ SEQ,   // (B,)    int32
              const float* __restrict__ W,     // (7D, K) f32
              const float* __restrict__ BIAS,  // (7D,)   f32
              const float* __restrict__ PROJ0, // (7D,)   f32
              unsigned short* __restrict__ HBUF, // (2,B,D) bf16 ping-pong
              int*   __restrict__ BCNT,        // 8 barrier counters (128B apart)
              int*   __restrict__ BGEN,        // 8 barrier generations
              float* __restrict__ OUT)         // f32: outputs (B,L,D) | final (B,4D)
{
    __shared__ float lds[4 * RW * PS];

    const int tid  = threadIdx.x;
    const int wid  = tid >> 6;      // wave 0..3
    const int lane = tid & 63;
    const int bid  = blockIdx.x;
    const int rg   = bid & 7;       // row group (XCD-local under round-robin)
    const int mg   = bid >> 3;      // m group
    const int b0   = rg * RW;
    const int m0   = mg * MW;

    // elementwise mapping: thread <-> (row, mi)
    const int erow = tid >> 4;
    const int emi  = tid & 15;
    const int eb   = b0 + erow;
    const int em   = m0 + emi;
    const int esl  = SEQ[eb];

    // MFMA lane mapping
    const int lrow = lane & 15;     // A row (batch) / B,C col
    const int lq   = lane >> 4;     // quad -> k-octet / C row block
    const int lb   = b0 + lrow;
    const int lsl  = SEQ[lb];

    int* bcnt = BCNT + rg * 32;     // 128 B apart
    int* bgen = BGEN + rg * 32;

    // ---- pin B fragments (weights, f32 -> bf16 RNE): Bf[i][g], K-step s=wid+4i
    bfrag8 Bf[6][7];
#pragma unroll
    for (int i = 0; i < 6; ++i) {
        const int s = wid + 4 * i;
        const int k = s * 32 + lq * 8;
#pragma unroll
        for (int g = 0; g < 7; ++g) {
            const int j = g * D_ + m0 + lrow;       // proj column
            const float4* wp = (const float4*)(W + (size_t)j * KTOT + k);
            Bf[i][g] = pack8(wp[0], wp[1]);
        }
    }

    // bias per elementwise thread (f32)
    float bg[7];
#pragma unroll
    for (int g = 0; g < 7; ++g) bg[g] = BIAS[g * D_ + em];

    // ---- initial state from BOS projection (same for every batch row)
    float p0[7];
#pragma unroll
    for (int g = 0; g < 7; ++g) p0[g] = PROJ0[g * D_ + em];
    float z0  = tanh_f(p0[5]);
    float so  = sigm(p0[4]);          // o
    float scs = sigm(p0[0]) * z0;     // cs = i*z  (c=0)
    float sce = sigm(p0[2]) * z0;     // ce = ie*z (ce=0)
    float sd  = softplus_f(p0[6]);    // d

    const size_t OUTF = (size_t)B_ * L_ * D_;   // final-state block offset (f32 elems)

    for (int t = 0; t < L_; ++t) {
        // ---- phase 1: decay + h (uses previous state; local)
        float dtt = (t < esl) ? DT[(size_t)eb * L_ + t] : 0.f;
        float c   = sce + (scs - sce) * __expf(-sd * dtt);
        float h   = so * tanh_f(c);
        HBUF[(size_t)((t & 1) * B_ + eb) * D_ + em] = f2bf(h);  // bf16 for MFMA feed
        OUT[((size_t)eb * L_ + t) * D_ + em]        = h;        // f32 output

        // ---- prefetch x fragments (s = wid, wid+4), f32 -> bf16
        bfrag8 ax[2];
#pragma unroll
        for (int i = 0; i < 2; ++i) {
            const int s = wid + 4 * i;
            const int k = s * 32 + lq * 8;
            float4 xa = {0.f, 0.f, 0.f, 0.f}, xb = {0.f, 0.f, 0.f, 0.f};
            if (t < lsl) {
                const float4* xp = (const float4*)(X + ((size_t)lb * L_ + t) * I_ + k);
                xa = xp[0]; xb = xp[1];
            }
            ax[i] = pack8(xa, xb);
        }

        gbar(bcnt, bgen, t + 1);   // h_t visible within row group; LDS fence

        // ---- load h fragments (s = 8..23 -> k within D), already bf16
        bfrag8 ah[4];
#pragma unroll
        for (int i = 2; i < 6; ++i) {
            const int s = wid + 4 * i;
            const int k = (s - 8) * 32 + lq * 8;
            ah[i - 2] = *(const bfrag8*)(HBUF + (size_t)((t & 1) * B_ + lb) * D_ + k);
        }

        // ---- MFMA: 6 K-steps x 7 N-tiles, fp32 accumulate
        f32x4 acc[7];
#pragma unroll
        for (int g = 0; g < 7; ++g) acc[g] = (f32x4){0.f, 0.f, 0.f, 0.f};
#pragma unroll
        for (int i = 0; i < 6; ++i) {
            const bfrag8 a = (i < 2) ? ax[i] : ah[i - 2];
#pragma unroll
            for (int g = 0; g < 7; ++g)
                acc[g] = __builtin_amdgcn_mfma_f32_16x16x32_bf16(a, Bf[i][g], acc[g], 0, 0, 0);
        }

        // ---- cross-wave K-reduction via LDS
        // C/D layout: col = lane&15, row = (lane>>4)*4 + reg  (m89/m91)
#pragma unroll
        for (int g = 0; g < 7; ++g)
#pragma unroll
            for (int r = 0; r < 4; ++r)
                lds[(wid * RW + lq * 4 + r) * PS + g * 16 + lrow] = acc[g][r];

        __syncthreads();

        // ---- phase 4: gates + state update (local)
        float p[7];
#pragma unroll
        for (int g = 0; g < 7; ++g) {
            float s = bg[g];
#pragma unroll
            for (int w2 = 0; w2 < 4; ++w2)
                s += lds[(w2 * RW + erow) * PS + g * 16 + emi];
            p[g] = s;
        }
        float ig  = sigm(p[0]);
        float fg  = sigm(p[1]);
        float ieg = sigm(p[2]);
        float feg = sigm(p[3]);
        float on  = sigm(p[4]);
        float z   = tanh_f(p[5]);
        float dn  = softplus_f(p[6]);
        float csn = fg * c + ig * z;
        float cen = feg * sce + ieg * z;
        so = on; scs = csn; sce = cen; sd = dn;

        if (t == esl - 1) {   // capture final state (post-update) at seq_len-1
            size_t fo = OUTF + (size_t)eb * (4 * D_) + em;
            OUT[fo]           = on;
            OUT[fo + D_]      = csn;
            OUT[fo + 2 * D_]  = cen;
            OUT[fo + 3 * D_]  = dn;
        }
        // next iteration's LDS writes happen after gbar's entry __syncthreads
    }
}

extern "C" void kernel_launch(void* const* d_in, const int* in_sizes, int n_in,
                              void* d_out, int out_size, void* d_ws, size_t ws_size,
                              hipStream_t stream) {
    const float* X   = (const float*)d_in[0];
    const float* DT  = (const float*)d_in[1];
    const int*   SEQ = (const int*)d_in[2];
    const float* BOS = (const float*)d_in[3];
    const float* W   = (const float*)d_in[4];
    const float* BI  = (const float*)d_in[5];
    float*       OUT = (float*)d_out;

    float*          proj0 = (float*)d_ws;                              // 14336 B
    int*            bcnt  = (int*)((char*)d_ws + 16384);               // 8 x 128 B
    int*            bgen  = (int*)((char*)d_ws + 16384 + 2048);        // 8 x 128 B
    unsigned short* hbuf  = (unsigned short*)((char*)d_ws + 32768);    // 2*B*D bf16 = 256 KB

    // barrier state must start at zero (d_ws is poisoned 0xAA each call)
    hipMemsetAsync((char*)d_ws + 16384, 0, 4096, stream);

    bos_proj_kernel<<<(ND7 + 255) / 256, 256, 0, stream>>>(W, BOS, BI, proj0);

    ctlstm_kernel<<<dim3(NWG), dim3(NTHR), 0, stream>>>(
        X, DT, SEQ, W, BI, proj0, hbuf, bcnt, bgen, OUT);
}